// Round 5
// baseline (341.594 us; speedup 1.0000x reference)
//
#include <hip/hip_runtime.h>
#include <stdint.h>
#include <stddef.h>

// ---- problem constants ----
#define K_CODES 1024
#define D_DIM   256
#define HW      1024      // 32*32 spatial
#define N_VEC   32768
#define TOT_ELEMS 8388608
#define NBLK    512       // vq_main grid

typedef float    v4f __attribute__((ext_vector_type(4)));
typedef _Float16 v8h __attribute__((ext_vector_type(8)));

// ------------------------------------------------------------------
// K1: codebook -> fp16 copy + 0.5*||e||^2 (+ zero loss_acc & counter).
__global__ void prep_emb(const float* __restrict__ emb,
                         _Float16* __restrict__ emb_h,
                         float* __restrict__ hnorm,
                         float* __restrict__ loss_acc,
                         unsigned* __restrict__ cnt) {
    int k = blockIdx.x, t = threadIdx.x;
    if (k == 0 && t == 0) { loss_acc[0] = 0.f; cnt[0] = 0u; }
    float v = emb[(size_t)k * D_DIM + t];
    emb_h[(size_t)k * D_DIM + t] = (_Float16)v;
    float s = v * v;
    for (int off = 32; off; off >>= 1) s += __shfl_down(s, off);
    __shared__ float wsum[4];
    if ((t & 63) == 0) wsum[t >> 6] = s;
    __syncthreads();
    if (t == 0) hnorm[k] = 0.5f * (wsum[0] + wsum[1] + wsum[2] + wsum[3]);
}

// ------------------------------------------------------------------
// K2: fused VQ, BARRIER-FREE main loop. 512 blocks x 512 thr (8 waves),
// 64 rows/block. B (codebook, 512 KB fp16) is L2-resident: load
// fragments DIRECTLY global->VGPR (no LDS staging, no ds traffic, no
// __syncthreads in the K loop -> compiler emits counted vmcnt, not the
// vmcnt(0) barrier drain that serialized all prior versions).
// 8 waves = 4 code-quarters (grp, 256 codes) x 2 row-halves (wv, 32
// rows: af0+af1, bf reused x2). bf double-buffered in named regs.
// dist' = 0.5||e||^2 - <z,e>; 4-way in-block argmin merge (ascending
// grp, strict < => lowest index). LDS ~39 KB + <=128 VGPR (512,4)
// -> 2 blocks/CU. Finalize folded via last-block ticket.
__global__ __launch_bounds__(512, 4) void
vq_main(const float* __restrict__ z,
        const _Float16* __restrict__ emb_h,
        const float* __restrict__ emb,
        const float* __restrict__ hnorm,
        float* __restrict__ out,
        float* __restrict__ loss_acc,
        unsigned* __restrict__ cnt) {
    __shared__ float  norm_s[K_CODES];
    __shared__ float  zq[32 * 257];
    __shared__ int    idx_s[64];
    __shared__ float2 mrg[3][2][32];
    __shared__ float  wred[8];

    int t    = threadIdx.x;
    int wave = t >> 6;
    int lane = t & 63;
    int grp  = wave >> 1;     // code quarter 0..3
    int wv   = wave & 1;      // 32-row half
    int col  = lane & 15;
    int quad = lane >> 4;
    int b    = blockIdx.x >> 4;
    int hw0  = (blockIdx.x & 15) * 64;
    const float* zb = z + (size_t)b * D_DIM * HW;

    for (int i = t; i < K_CODES; i += 512) norm_s[i] = hnorm[i];
    __syncthreads();          // norm_s ready; ONLY barrier before epilogue

    // A fragments: 32 rows/wave (af0: rows m0.., af1: rows m0+16..)
    int m0 = hw0 + wv * 32;
    v8h af0[8], af1[8];
#pragma unroll
    for (int c = 0; c < 8; ++c) {
#pragma unroll
        for (int j = 0; j < 8; ++j) {
            int d = c * 32 + quad * 8 + j;
            const float* p = zb + (size_t)d * HW + m0 + col;
            af0[c][j] = (_Float16)p[0];
            af1[c][j] = (_Float16)p[16];
        }
    }

    // B fragment base for this wave: code row + quad's 8-dim granule.
    // bf[c] = e[code][c*32 + quad*8 .. +7]  (matches af layout)
    const _Float16* eb = emb_h + ((size_t)grp * 256) * D_DIM + quad * 8;

    float minv[8]; int mini[8];
#pragma unroll
    for (int r = 0; r < 8; ++r) { minv[r] = 3.4e38f; mini[r] = 0; }

    v8h bfA[8], bfB[8];
    auto loadB = [&](int T, v8h* bf) {
        const _Float16* p = eb + (size_t)(T * 16 + col) * D_DIM;
#pragma unroll
        for (int c = 0; c < 8; ++c)
            bf[c] = *(const v8h*)(p + c * 32);
    };
    auto compT = [&](int T, const v8h* bf) {
        v4f acc0 = {0.f, 0.f, 0.f, 0.f};
        v4f acc1 = {0.f, 0.f, 0.f, 0.f};
#pragma unroll
        for (int c = 0; c < 8; ++c) {
            acc0 = __builtin_amdgcn_mfma_f32_16x16x32_f16(af0[c], bf[c], acc0, 0, 0, 0);
            acc1 = __builtin_amdgcn_mfma_f32_16x16x32_f16(af1[c], bf[c], acc1, 0, 0, 0);
        }
        int   code = grp * 256 + T * 16 + col;
        float n    = norm_s[code];
#pragma unroll
        for (int r = 0; r < 4; ++r) {
            float d0 = n - acc0[r];
            if (d0 < minv[r])     { minv[r]     = d0; mini[r]     = code; }
            float d1 = n - acc1[r];
            if (d1 < minv[4 + r]) { minv[4 + r] = d1; mini[4 + r] = code; }
        }
    };

    loadB(0, bfA);
    for (int T = 0; T < 16; T += 2) {     // no barriers: free-running pipe
        loadB(T + 1, bfB);
        compT(T, bfA);
        if (T + 2 < 16) loadB(T + 2, bfA);
        compT(T + 1, bfB);
    }

    // reduce across the 16 cols of each quad
#pragma unroll
    for (int off = 1; off < 16; off <<= 1) {
#pragma unroll
        for (int r = 0; r < 8; ++r) {
            float ov = __shfl_xor(minv[r], off);
            int   oi = __shfl_xor(mini[r], off);
            if (ov < minv[r] || (ov == minv[r] && oi < mini[r])) {
                minv[r] = ov; mini[r] = oi;
            }
        }
    }
    // 4-way quarter merge: grp 1..3 post, grp 0 merges in ascending
    // code order (strict < keeps lowest index).
    if (grp != 0 && col == 0) {
#pragma unroll
        for (int r = 0; r < 8; ++r) {
            int rl = (r >> 2) * 16 + quad * 4 + (r & 3);
            mrg[grp - 1][wv][rl] = make_float2(minv[r], __int_as_float(mini[r]));
        }
    }
    __syncthreads();
    if (grp == 0 && col == 0) {
#pragma unroll
        for (int r = 0; r < 8; ++r) {
            int rl = (r >> 2) * 16 + quad * 4 + (r & 3);
            float bv = minv[r]; int bi = mini[r];
#pragma unroll
            for (int h = 0; h < 3; ++h) {
                float2 m2 = mrg[h][wv][rl];
                if (m2.x < bv) { bv = m2.x; bi = __float_as_int(m2.y); }
            }
            idx_s[wv * 32 + rl] = bi;
        }
    }
    __syncthreads();

    // ---- epilogue: gather emb rows -> LDS, write out + fused loss ----
    // 64 rows in two 32-row passes; all 8 waves cooperate.
    int tt = t & 255, th = t >> 8;            // th in {0,1}
    float sum = 0.f;
    for (int s = 0; s < 2; ++s) {
        if (s) __syncthreads();
#pragma unroll
        for (int ii = 0; ii < 16; ++ii) {
            int i = th * 16 + ii;
            zq[i * 257 + tt] =
                emb[(size_t)idx_s[s * 32 + i] * D_DIM + tt];
        }
        __syncthreads();
        int j = t & 31, dblk = t >> 5;        // dblk 0..15
#pragma unroll
        for (int p = 0; p < 16; ++p) {
            int d = dblk * 16 + p;
            size_t o = (size_t)(b * D_DIM + d) * HW
                       + hw0 + s * 32 + j;
            float q  = zq[j * 257 + d];
            float e  = z[o];
            float df = q - e;
            sum += df * df;
            out[o] = q;                 // z_q_st == z_q numerically
        }
    }
    for (int off = 32; off; off >>= 1) sum += __shfl_down(sum, off);
    if (lane == 0) wred[wave] = sum;
    __syncthreads();
    if (t == 0) {
        float s8 = 0.f;
#pragma unroll
        for (int i = 0; i < 8; ++i) s8 += wred[i];
        atomicAdd(loss_acc, s8);
        __threadfence();
        if (atomicAdd(cnt, 1u) == NBLK - 1) {
            // all blocks' loss adds are visible at the L2 atomic point
            float total = atomicAdd(loss_acc, 0.0f);
            out[TOT_ELEMS] = total * (1.25f / (float)TOT_ELEMS);
        }
    }
}

// ------------------------------------------------------------------
extern "C" void kernel_launch(void* const* d_in, const int* in_sizes, int n_in,
                              void* d_out, int out_size, void* d_ws, size_t ws_size,
                              hipStream_t stream) {
    const float* z   = (const float*)d_in[0];   // [32,256,32,32]
    const float* emb = (const float*)d_in[1];   // [1024,256]
    float* out = (float*)d_out;                 // [8388608 z_q_st][1 loss]

    char* ws = (char*)d_ws;
    float*    loss_acc = (float*)ws;            // @0
    unsigned* cnt      = (unsigned*)(ws + 4);   // last-block ticket
    float*    hnorm    = (float*)(ws + 1024);   // 4 KB
    _Float16* emb_h    = (_Float16*)(ws + 8192);// 512 KB

    prep_emb<<<dim3(K_CODES), dim3(256), 0, stream>>>(emb, emb_h, hnorm,
                                                      loss_acc, cnt);
    vq_main<<<dim3(NBLK), dim3(512), 0, stream>>>(z, emb_h, emb, hnorm,
                                                  out, loss_acc, cnt);
}

// Round 6
// 200.315 us; speedup vs baseline: 1.7053x; 1.7053x over previous
//
#include <hip/hip_runtime.h>
#include <stdint.h>
#include <stddef.h>

// ---- problem constants ----
#define K_CODES 1024
#define D_DIM   256
#define HW      1024      // 32*32 spatial
#define N_VEC   32768
#define TOT_ELEMS 8388608
#define NBLK    1024      // vq_main grid

typedef float    v4f __attribute__((ext_vector_type(4)));
typedef _Float16 v8h __attribute__((ext_vector_type(8)));

// ------------------------------------------------------------------
// K1: codebook -> fp16 copy + 0.5*||e||^2 (+ zero loss_acc & counter).
__global__ void prep_emb(const float* __restrict__ emb,
                         _Float16* __restrict__ emb_h,
                         float* __restrict__ hnorm,
                         float* __restrict__ loss_acc,
                         unsigned* __restrict__ cnt) {
    int k = blockIdx.x, t = threadIdx.x;
    if (k == 0 && t == 0) { loss_acc[0] = 0.f; cnt[0] = 0u; }
    float v = emb[(size_t)k * D_DIM + t];
    emb_h[(size_t)k * D_DIM + t] = (_Float16)v;
    float s = v * v;
    for (int off = 32; off; off >>= 1) s += __shfl_down(s, off);
    __shared__ float wsum[4];
    if ((t & 63) == 0) wsum[t >> 6] = s;
    __syncthreads();
    if (t == 0) hnorm[k] = 0.5f * (wsum[0] + wsum[1] + wsum[2] + wsum[3]);
}

// ------------------------------------------------------------------
// K2: fused VQ, BARRIER-FREE main loop. 1024 blocks x 256 thr (4
// waves), 32 rows/block. B (codebook, 512 KB fp16) is L2-resident:
// fragments loaded DIRECTLY global->VGPR (no LDS staging, no main-loop
// __syncthreads -> counted vmcnt instead of barrier vmcnt(0) drains).
// 4 waves = 4 code-quarters (grp, 256 codes each); every wave owns the
// same 32 rows (af0+af1 => each bf reused x2). bf double-buffered in
// named arrays with ALL-STATIC indexing (macros + full unroll; R5's
// pointer-param lambdas caused a wholesale scratch spill: VGPR 64,
// WRITE_SIZE 528 MB). Live set ~164 VGPR -> __launch_bounds__(256,2)
// (256-reg cap, no spill), LDS ~38 KB => 2-3 blocks/CU.
// dist' = 0.5||e||^2 - <z,e>; 4-way in-block argmin merge (ascending
// grp, strict < => lowest index). Finalize folded via ticket.

#define LOADB(buf, T) do {                                              \
    const _Float16* p_ = eb + (size_t)((T) * 16 + col) * D_DIM;         \
    _Pragma("unroll")                                                   \
    for (int c_ = 0; c_ < 8; ++c_)                                      \
        buf[c_] = *(const v8h*)(p_ + c_ * 32);                          \
} while (0)

#define COMPT(buf, T) do {                                              \
    v4f a0_ = {0.f, 0.f, 0.f, 0.f};                                     \
    v4f a1_ = {0.f, 0.f, 0.f, 0.f};                                     \
    _Pragma("unroll")                                                   \
    for (int c_ = 0; c_ < 8; ++c_) {                                    \
        a0_ = __builtin_amdgcn_mfma_f32_16x16x32_f16(af0[c_], buf[c_], a0_, 0, 0, 0); \
        a1_ = __builtin_amdgcn_mfma_f32_16x16x32_f16(af1[c_], buf[c_], a1_, 0, 0, 0); \
    }                                                                   \
    int   code_ = grp * 256 + (T) * 16 + col;                           \
    float n_    = norm_s[code_];                                        \
    _Pragma("unroll")                                                   \
    for (int r_ = 0; r_ < 4; ++r_) {                                    \
        float d0_ = n_ - a0_[r_];                                       \
        if (d0_ < minv[r_])     { minv[r_]     = d0_; mini[r_]     = code_; } \
        float d1_ = n_ - a1_[r_];                                       \
        if (d1_ < minv[4 + r_]) { minv[4 + r_] = d1_; mini[4 + r_] = code_; } \
    }                                                                   \
} while (0)

__global__ __launch_bounds__(256, 2) void
vq_main(const float* __restrict__ z,
        const _Float16* __restrict__ emb_h,
        const float* __restrict__ emb,
        const float* __restrict__ hnorm,
        float* __restrict__ out,
        float* __restrict__ loss_acc,
        unsigned* __restrict__ cnt) {
    __shared__ float  norm_s[K_CODES];
    __shared__ float  zq[32 * 257];
    __shared__ int    idx_s[32];
    __shared__ float2 mrg[3][32];
    __shared__ float  wred[4];

    int t    = threadIdx.x;
    int grp  = t >> 6;        // wave = code quarter 0..3
    int lane = t & 63;
    int col  = lane & 15;
    int quad = lane >> 4;
    int b    = blockIdx.x >> 5;
    int hw0  = (blockIdx.x & 31) * 32;
    const float* zb = z + (size_t)b * D_DIM * HW;

    for (int i = t; i < K_CODES; i += 256) norm_s[i] = hnorm[i];
    __syncthreads();          // norm_s ready; only barrier before merge

    // A fragments: 32 rows (af0: rows hw0+col, af1: rows hw0+16+col)
    v8h af0[8], af1[8];
#pragma unroll
    for (int c = 0; c < 8; ++c) {
#pragma unroll
        for (int j = 0; j < 8; ++j) {
            int d = c * 32 + quad * 8 + j;
            const float* p = zb + (size_t)d * HW + hw0 + col;
            af0[c][j] = (_Float16)p[0];
            af1[c][j] = (_Float16)p[16];
        }
    }

    // B fragment base: this wave's quarter + quad's 8-dim granule.
    const _Float16* eb = emb_h + ((size_t)grp * 256) * D_DIM + quad * 8;

    float minv[8]; int mini[8];
#pragma unroll
    for (int r = 0; r < 8; ++r) { minv[r] = 3.4e38f; mini[r] = 0; }

    v8h bf0[8], bf1[8];
    LOADB(bf0, 0);
#pragma unroll
    for (int T = 0; T < 16; T += 2) {     // no barriers: free-running
        LOADB(bf1, T + 1);
        COMPT(bf0, T);
        if (T + 2 < 16) LOADB(bf0, T + 2);
        COMPT(bf1, T + 1);
    }

    // reduce across the 16 cols of each quad
#pragma unroll
    for (int off = 1; off < 16; off <<= 1) {
#pragma unroll
        for (int r = 0; r < 8; ++r) {
            float ov = __shfl_xor(minv[r], off);
            int   oi = __shfl_xor(mini[r], off);
            if (ov < minv[r] || (ov == minv[r] && oi < mini[r])) {
                minv[r] = ov; mini[r] = oi;
            }
        }
    }
    // 4-way quarter merge: grp 1..3 post, grp 0 merges in ascending
    // code order (strict < keeps lowest index).
    if (grp != 0 && col == 0) {
#pragma unroll
        for (int r = 0; r < 8; ++r) {
            int rl = (r >> 2) * 16 + quad * 4 + (r & 3);
            mrg[grp - 1][rl] = make_float2(minv[r], __int_as_float(mini[r]));
        }
    }
    __syncthreads();
    if (grp == 0 && col == 0) {
#pragma unroll
        for (int r = 0; r < 8; ++r) {
            int rl = (r >> 2) * 16 + quad * 4 + (r & 3);
            float bv = minv[r]; int bi = mini[r];
#pragma unroll
            for (int h = 0; h < 3; ++h) {
                float2 m2 = mrg[h][rl];
                if (m2.x < bv) { bv = m2.x; bi = __float_as_int(m2.y); }
            }
            idx_s[rl] = bi;
        }
    }
    __syncthreads();

    // ---- epilogue: gather emb rows -> LDS, write out + fused loss ----
    // 32 rows; all 4 waves cooperate. zq row-stride 257 -> conflict-free.
#pragma unroll 4
    for (int i = 0; i < 32; ++i)
        zq[i * 257 + t] = emb[(size_t)idx_s[i] * D_DIM + t];
    __syncthreads();
    int j = t & 31, dblk = t >> 5;        // dblk 0..7
    float sum = 0.f;
#pragma unroll 4
    for (int p = 0; p < 32; ++p) {
        int d = dblk * 32 + p;
        size_t o = (size_t)(b * D_DIM + d) * HW + hw0 + j;
        float q  = zq[j * 257 + d];
        float e  = z[o];
        float df = q - e;
        sum += df * df;
        out[o] = q;                 // z_q_st == z_q numerically
    }
    for (int off = 32; off; off >>= 1) sum += __shfl_down(sum, off);
    if (lane == 0) wred[t >> 6] = sum;
    __syncthreads();
    if (t == 0) {
        float s4 = wred[0] + wred[1] + wred[2] + wred[3];
        atomicAdd(loss_acc, s4);
        __threadfence();
        if (atomicAdd(cnt, 1u) == NBLK - 1) {
            // all blocks' loss adds are visible at the L2 atomic point
            float total = atomicAdd(loss_acc, 0.0f);
            out[TOT_ELEMS] = total * (1.25f / (float)TOT_ELEMS);
        }
    }
}

// ------------------------------------------------------------------
extern "C" void kernel_launch(void* const* d_in, const int* in_sizes, int n_in,
                              void* d_out, int out_size, void* d_ws, size_t ws_size,
                              hipStream_t stream) {
    const float* z   = (const float*)d_in[0];   // [32,256,32,32]
    const float* emb = (const float*)d_in[1];   // [1024,256]
    float* out = (float*)d_out;                 // [8388608 z_q_st][1 loss]

    char* ws = (char*)d_ws;
    float*    loss_acc = (float*)ws;            // @0
    unsigned* cnt      = (unsigned*)(ws + 4);   // last-block ticket
    float*    hnorm    = (float*)(ws + 1024);   // 4 KB
    _Float16* emb_h    = (_Float16*)(ws + 8192);// 512 KB

    prep_emb<<<dim3(K_CODES), dim3(256), 0, stream>>>(emb, emb_h, hnorm,
                                                      loss_acc, cnt);
    vq_main<<<dim3(NBLK), dim3(256), 0, stream>>>(z, emb_h, emb, hnorm,
                                                  out, loss_acc, cnt);
}

// Round 8
// 131.459 us; speedup vs baseline: 2.5985x; 1.5238x over previous
//
#include <hip/hip_runtime.h>
#include <stdint.h>
#include <stddef.h>

// ---- problem constants ----
#define K_CODES 1024
#define D_DIM   256
#define HW      1024      // 32*32 spatial
#define N_VEC   32768
#define TOT_ELEMS 8388608
#define NBLK    256       // vq_main grid

typedef float    v4f __attribute__((ext_vector_type(4)));
typedef _Float16 v8h __attribute__((ext_vector_type(8)));

// async global->LDS, 16B/lane, dest = wave-uniform base + lane*16
__device__ __forceinline__ void gld_lds16(const void* g, void* l) {
    __builtin_amdgcn_global_load_lds(
        (const __attribute__((address_space(1))) void*)g,
        (__attribute__((address_space(3))) void*)l, 16, 0, 0);
}

// ------------------------------------------------------------------
// K1: codebook -> fp16 copy + 0.5*||e||^2 (+ zero loss_acc & counter).
__global__ void prep_emb(const float* __restrict__ emb,
                         _Float16* __restrict__ emb_h,
                         float* __restrict__ hnorm,
                         float* __restrict__ loss_acc,
                         unsigned* __restrict__ cnt) {
    int k = blockIdx.x, t = threadIdx.x;
    if (k == 0 && t == 0) { loss_acc[0] = 0.f; cnt[0] = 0u; }
    float v = emb[(size_t)k * D_DIM + t];
    emb_h[(size_t)k * D_DIM + t] = (_Float16)v;
    float s = v * v;
    for (int off = 32; off; off >>= 1) s += __shfl_down(s, off);
    __shared__ float wsum[4];
    if ((t & 63) == 0) wsum[t >> 6] = s;
    __syncthreads();
    if (t == 0) hnorm[k] = 0.5f * (wsum[0] + wsum[1] + wsum[2] + wsum[3]);
}

// ------------------------------------------------------------------
// K2: fused VQ — baseline structure (proven 49.5us) + doubled wave
// count. 256 blocks x 1024 thr (16 waves), 128 rows/block, 1 block/CU
// (LDS ~136 KB) but 4 waves/SIMD (vs baseline's 2) for latency hiding.
// 16 waves = 4 code-quarters (grp, 256 codes) x 4 row-tiles (wv, 32
// rows via af0/af1). Per-block totals IDENTICAL to baseline: 2048
// ds_read_b128, 4096 MFMA, B staged once (512 KB). Tiles: 32 codes
// (16 KB/grp), double-buffered, 1 __syncthreads per tile (steady-state
// drain cheap: stage issued a full tile-compute earlier).
// Swizzle: granule g of code k at slot u = g ^ (k&7) (baseline).
// dist' = 0.5||e||^2 - <z,e>; 4-way merge ascending grp, strict < =>
// lowest index. LOSS computed from argmin value: loss_row =
// ||z_row||^2 (fp32, from A-prologue) + 2*minv_win  — removes the
// epilogue z re-read entirely. Finalize folded via ticket.
__global__ __launch_bounds__(1024, 4) void
vq_main(const float* __restrict__ z,
        const _Float16* __restrict__ emb_h,
        const float* __restrict__ emb,
        const float* __restrict__ hnorm,
        float* __restrict__ out,
        float* __restrict__ loss_acc,
        unsigned* __restrict__ cnt) {
    // btile: [4 grp][2 buf][16 KB] = 128 KB; epilogue zq overlays
    // (64 rows x 257 floats = 65.8 KB <= 128 KB).
    __shared__ __align__(16) char smem[131072];
    __shared__ float  norm_s[K_CODES];
    __shared__ int    idx_s[128];
    __shared__ float2 mrg[3][4][32];
    __shared__ float  wred[4];

    int t    = threadIdx.x;
    int wave = t >> 6;
    int lane = t & 63;
    int grp  = wave >> 2;     // code quarter 0..3 (256 codes each)
    int wv   = wave & 3;      // 32-row tile selector
    int col  = lane & 15;
    int quad = lane >> 4;
    int b    = blockIdx.x >> 3;
    int hw0  = (blockIdx.x & 7) * 128;
    const float* zb = z + (size_t)b * D_DIM * HW;

    // stage tile T (32 codes, 16 KB) of this wave's quarter; the four
    // waves sharing a quarter (wv 0..3) each stage 8 codes (4 KB).
    auto stage = [&](int buf, int T) {
        const char* src = (const char*)emb_h
                          + (size_t)(grp * 256 + T * 32) * 512;
        char* dst = (char*)smem + (grp * 2 + buf) * 16384 + wv * 4096;
#pragma unroll
        for (int i = 0; i < 4; ++i) {
            int kloc = wv * 8 + i * 2 + (lane >> 5);
            int g    = (lane & 31) ^ (kloc & 7);
            gld_lds16(src + (size_t)kloc * 512 + (size_t)g * 16,
                      dst + i * 1024);
        }
    };
    stage(0, 0);

    if (t < K_CODES) norm_s[t] = hnorm[t];

    // A fragments: 32 rows/wave (af0: m0+col, af1: m0+16+col), plus
    // fp32 row-norms for the loss (z2a/z2b).
    int m0 = hw0 + wv * 32;
    v8h af0[8], af1[8];
    float z2a = 0.f, z2b = 0.f;
#pragma unroll
    for (int c = 0; c < 8; ++c) {
#pragma unroll
        for (int j = 0; j < 8; ++j) {
            int d = c * 32 + quad * 8 + j;
            const float* p = zb + (size_t)d * HW + m0 + col;
            float v0 = p[0], v1 = p[16];
            af0[c][j] = (_Float16)v0;
            af1[c][j] = (_Float16)v1;
            z2a += v0 * v0;
            z2b += v1 * v1;
        }
    }
    // combine the 4 quad-lanes: every lane then holds full row norms
    z2a += __shfl_xor(z2a, 16); z2a += __shfl_xor(z2a, 32);
    z2b += __shfl_xor(z2b, 16); z2b += __shfl_xor(z2b, 32);

    float minv[8]; int mini[8];
#pragma unroll
    for (int r = 0; r < 8; ++r) { minv[r] = 3.4e38f; mini[r] = 0; }

    for (int T = 0; T < 8; ++T) {
        __syncthreads();                 // tile T staged (issued 1 iter ago)
        if (T < 7) stage((T + 1) & 1, T + 1);
        const _Float16* bt =
            (const _Float16*)(smem + (size_t)(grp * 2 + (T & 1)) * 16384);
#pragma unroll
        for (int cc = 0; cc < 2; ++cc) {
            int k = cc * 16 + col;
            v8h bf[8];
#pragma unroll
            for (int c = 0; c < 8; ++c) {
                int u = (c * 4 + quad) ^ (col & 7);   // k&7 == col&7
                bf[c] = *(const v8h*)(bt + (size_t)k * D_DIM + (u << 3));
            }
            v4f acc0 = {0.f, 0.f, 0.f, 0.f};
            v4f acc1 = {0.f, 0.f, 0.f, 0.f};
#pragma unroll
            for (int c = 0; c < 8; ++c) {
                acc0 = __builtin_amdgcn_mfma_f32_16x16x32_f16(af0[c], bf[c], acc0, 0, 0, 0);
                acc1 = __builtin_amdgcn_mfma_f32_16x16x32_f16(af1[c], bf[c], acc1, 0, 0, 0);
            }
            int   code = grp * 256 + T * 32 + k;
            float n    = norm_s[code];
#pragma unroll
            for (int r = 0; r < 4; ++r) {
                float d0 = n - acc0[r];
                if (d0 < minv[r])     { minv[r]     = d0; mini[r]     = code; }
                float d1 = n - acc1[r];
                if (d1 < minv[4 + r]) { minv[4 + r] = d1; mini[4 + r] = code; }
            }
        }
    }
    // reduce across the 16 cols of each quad
#pragma unroll
    for (int off = 1; off < 16; off <<= 1) {
#pragma unroll
        for (int r = 0; r < 8; ++r) {
            float ov = __shfl_xor(minv[r], off);
            int   oi = __shfl_xor(mini[r], off);
            if (ov < minv[r] || (ov == minv[r] && oi < mini[r])) {
                minv[r] = ov; mini[r] = oi;
            }
        }
    }
    // 4-way quarter merge: grp 1..3 post, grp 0 merges in ascending
    // code order (strict < keeps lowest index) + computes the loss.
    if (grp != 0 && col == 0) {
#pragma unroll
        for (int r = 0; r < 8; ++r) {
            int rl = (r >> 2) * 16 + quad * 4 + (r & 3);
            mrg[grp - 1][wv][rl] = make_float2(minv[r], __int_as_float(mini[r]));
        }
    }
    __syncthreads();
    float lsum = 0.f;
    if (grp == 0) {
        // row-norms for this wave's rows rl = (r>>2)*16 + quad*4 + (r&3)
        float z2r[8];
#pragma unroll
        for (int r = 0; r < 4; ++r) {
            z2r[r]     = __shfl(z2a, quad * 4 + r);   // rows 0..15
            z2r[4 + r] = __shfl(z2b, quad * 4 + r);   // rows 16..31
        }
        if (col == 0) {
#pragma unroll
            for (int r = 0; r < 8; ++r) {
                int rl = (r >> 2) * 16 + quad * 4 + (r & 3);
                float bv = minv[r]; int bi = mini[r];
#pragma unroll
                for (int h = 0; h < 3; ++h) {
                    float2 m2 = mrg[h][wv][rl];
                    if (m2.x < bv) { bv = m2.x; bi = __float_as_int(m2.y); }
                }
                idx_s[wv * 32 + rl] = bi;
                // ||z-e||^2 = ||z||^2 + 2*(0.5||e||^2 - <z,e>)
                lsum += z2r[r] + 2.f * bv;
            }
        }
        // sum the 4 col==0 lanes (0,16,32,48) -> lane 0
        lsum += __shfl_xor(lsum, 16);
        lsum += __shfl_xor(lsum, 32);
        if (lane == 0) wred[wv] = lsum;
    }
    __syncthreads();

    // ---- epilogue: gather emb rows -> LDS, write out (no z re-read) --
    // 128 rows in two 64-row passes; all 16 waves cooperate.
    float* zq = (float*)smem;                 // 64 x 257 floats
    int tt = t & 255, th = t >> 8;            // th in {0..3}
    for (int s = 0; s < 2; ++s) {
        if (s) __syncthreads();
#pragma unroll
        for (int ii = 0; ii < 16; ++ii) {
            int i = th * 16 + ii;
            zq[i * 257 + tt] =
                emb[(size_t)idx_s[s * 64 + i] * D_DIM + tt];
        }
        __syncthreads();
        int j = t & 63, dblk = t >> 6;        // dblk 0..15
#pragma unroll
        for (int p = 0; p < 16; ++p) {
            int d = dblk * 16 + p;
            size_t o = (size_t)(b * D_DIM + d) * HW
                       + hw0 + s * 64 + j;
            out[o] = zq[j * 257 + d];         // z_q_st == z_q numerically
        }
    }
    if (t == 0) {
        float s4 = wred[0] + wred[1] + wred[2] + wred[3];
        atomicAdd(loss_acc, s4);
        __threadfence();
        if (atomicAdd(cnt, 1u) == NBLK - 1) {
            // all blocks' loss adds are visible at the L2 atomic point
            float total = atomicAdd(loss_acc, 0.0f);
            out[TOT_ELEMS] = total * (1.25f / (float)TOT_ELEMS);
        }
    }
}

// ------------------------------------------------------------------
extern "C" void kernel_launch(void* const* d_in, const int* in_sizes, int n_in,
                              void* d_out, int out_size, void* d_ws, size_t ws_size,
                              hipStream_t stream) {
    const float* z   = (const float*)d_in[0];   // [32,256,32,32]
    const float* emb = (const float*)d_in[1];   // [1024,256]
    float* out = (float*)d_out;                 // [8388608 z_q_st][1 loss]

    char* ws = (char*)d_ws;
    float*    loss_acc = (float*)ws;            // @0
    unsigned* cnt      = (unsigned*)(ws + 4);   // last-block ticket
    float*    hnorm    = (float*)(ws + 1024);   // 4 KB
    _Float16* emb_h    = (_Float16*)(ws + 8192);// 512 KB

    prep_emb<<<dim3(K_CODES), dim3(256), 0, stream>>>(emb, emb_h, hnorm,
                                                      loss_acc, cnt);
    vq_main<<<dim3(NBLK), dim3(1024), 0, stream>>>(z, emb_h, emb, hnorm,
                                                   out, loss_acc, cnt);
}

// Round 12
// 124.525 us; speedup vs baseline: 2.7432x; 1.0557x over previous
//
#include <hip/hip_runtime.h>
#include <stdint.h>
#include <stddef.h>

// ---- problem constants ----
#define K_CODES 1024
#define D_DIM   256
#define HW      1024      // 32*32 spatial
#define N_VEC   32768
#define TOT_ELEMS 8388608
#define NBLK    256       // vq_main grid

typedef float    v4f __attribute__((ext_vector_type(4)));
typedef _Float16 v8h __attribute__((ext_vector_type(8)));

// async global->LDS, 16B/lane, dest = wave-uniform base + lane*16
__device__ __forceinline__ void gld_lds16(const void* g, void* l) {
    __builtin_amdgcn_global_load_lds(
        (const __attribute__((address_space(1))) void*)g,
        (__attribute__((address_space(3))) void*)l, 16, 0, 0);
}

// ------------------------------------------------------------------
// K1: codebook -> fp16 copy + 0.5*||e||^2 (+ zero loss_acc & counter,
// replacing the old hipMemsetAsync graph node).
__global__ void prep_emb(const float* __restrict__ emb,
                         _Float16* __restrict__ emb_h,
                         float* __restrict__ hnorm,
                         float* __restrict__ loss_acc,
                         unsigned* __restrict__ cnt) {
    int k = blockIdx.x, t = threadIdx.x;
    if (k == 0 && t == 0) { loss_acc[0] = 0.f; cnt[0] = 0u; }
    float v = emb[(size_t)k * D_DIM + t];
    emb_h[(size_t)k * D_DIM + t] = (_Float16)v;
    float s = v * v;
    for (int off = 32; off; off >>= 1) s += __shfl_down(s, off);
    __shared__ float wsum[4];
    if ((t & 63) == 0) wsum[t >> 6] = s;
    __syncthreads();
    if (t == 0) hnorm[k] = 0.5f * (wsum[0] + wsum[1] + wsum[2] + wsum[3]);
}

// ------------------------------------------------------------------
// K2: fused VQ — EXACT baseline main-loop structure (proven 49.5us:
// 256 blocks x 512 thr, 128 rows/block, 2-way K-split, 64-code
// double-buffered tiles, swizzle u = g ^ (k&7), VGPR ~92 under the
// 2-waves/SIMD 256-reg cap -> no spill) + two proven grafts:
//  (1) loss-from-argmin: fp32 row-norms in the A-prologue;
//      loss_row = ||z||^2 + 2*(0.5||e||^2 - <z,e>)_win at merge.
//      Epilogue z re-read and MSE pass deleted (R8: FETCH -9 MB,
//      absmax unchanged).
//  (2) finalize folded via last-block ticket (2-node graph).
__global__ __launch_bounds__(512, 2) void
vq_main(const float* __restrict__ z,
        const _Float16* __restrict__ emb_h,
        const float* __restrict__ emb,
        const float* __restrict__ hnorm,
        float* __restrict__ out,
        float* __restrict__ loss_acc,
        unsigned* __restrict__ cnt) {
    __shared__ __align__(16) char smem[131072];   // btile[2grp][2buf][32KB] / zq
    __shared__ float  norm_s[K_CODES];
    __shared__ int    idx_s[128];
    __shared__ float2 mrg[4][32];
    __shared__ float  wred[4];

    _Float16* btile = (_Float16*)smem;

    int t    = threadIdx.x;
    int wave = t >> 6;
    int lane = t & 63;
    int grp  = wave >> 2;     // K-half
    int wv   = wave & 3;      // row-tile selector
    int col  = lane & 15;
    int quad = lane >> 4;
    int b    = blockIdx.x >> 3;
    int hw0  = (blockIdx.x & 7) * 128;
    const float* zb = z + (size_t)b * D_DIM * HW;

    // stage tile T (64 codes, 32 KB) of this wave's K-half
    auto stage = [&](int buf, int T) {
        const char* src = (const char*)(emb_h
                          + (size_t)(grp * 512 + T * 64) * D_DIM);
        char* dst = (char*)(btile + (size_t)(grp * 2 + buf) * 16384)
                    + wv * 8192;
#pragma unroll
        for (int i = 0; i < 8; ++i) {
            int k = wv * 16 + i * 2 + (lane >> 5);
            int g = (lane & 31) ^ (k & 7);
            gld_lds16(src + (size_t)k * 512 + (size_t)g * 16, dst + i * 1024);
        }
    };
    stage(0, 0);

    for (int i = t; i < K_CODES; i += 512) norm_s[i] = hnorm[i];

    // A fragments (32 rows/wave, both K-halves load same rows) + fp32
    // row-norm partials for the fused loss.
    int m0w = hw0 + wv * 32;
    v8h af0[8], af1[8];
    float z2a = 0.f, z2b = 0.f;
#pragma unroll
    for (int c = 0; c < 8; ++c) {
#pragma unroll
        for (int j = 0; j < 8; ++j) {
            int d = c * 32 + quad * 8 + j;
            const float* p = zb + (size_t)d * HW + m0w + col;
            float v0 = p[0], v1 = p[16];
            af0[c][j] = (_Float16)v0;
            af1[c][j] = (_Float16)v1;
            z2a += v0 * v0;
            z2b += v1 * v1;
        }
    }
    // lanes col, col+16, col+32, col+48 all end with full norm of row m0w+col
    z2a += __shfl_xor(z2a, 16); z2a += __shfl_xor(z2a, 32);
    z2b += __shfl_xor(z2b, 16); z2b += __shfl_xor(z2b, 32);

    float minv[8]; int mini[8];
#pragma unroll
    for (int r = 0; r < 8; ++r) { minv[r] = 3.4e38f; mini[r] = 0; }

    for (int T = 0; T < 8; ++T) {
        __syncthreads();                 // staged buffer ready
        if (T < 7) stage((T + 1) & 1, T + 1);
        const _Float16* bt = btile + (size_t)(grp * 2 + (T & 1)) * 16384;
#pragma unroll
        for (int cc = 0; cc < 4; ++cc) {
            int k = cc * 16 + col;
            v8h bf[8];
#pragma unroll
            for (int c = 0; c < 8; ++c) {
                int u = (c * 4 + quad) ^ (col & 7);   // k&7 == col&7
                bf[c] = *(const v8h*)(bt + (size_t)k * D_DIM + (u << 3));
            }
            v4f acc0 = {0.f, 0.f, 0.f, 0.f};
            v4f acc1 = {0.f, 0.f, 0.f, 0.f};
#pragma unroll
            for (int c = 0; c < 8; ++c) {
                acc0 = __builtin_amdgcn_mfma_f32_16x16x32_f16(af0[c], bf[c], acc0, 0, 0, 0);
                acc1 = __builtin_amdgcn_mfma_f32_16x16x32_f16(af1[c], bf[c], acc1, 0, 0, 0);
            }
            int   code = grp * 512 + T * 64 + k;
            float n    = norm_s[code];
#pragma unroll
            for (int r = 0; r < 4; ++r) {
                float d0 = n - acc0[r];
                if (d0 < minv[r])     { minv[r]     = d0; mini[r]     = code; }
                float d1 = n - acc1[r];
                if (d1 < minv[4 + r]) { minv[4 + r] = d1; mini[4 + r] = code; }
            }
        }
    }
    // reduce across the 16 cols of each quad
#pragma unroll
    for (int off = 1; off < 16; off <<= 1) {
#pragma unroll
        for (int r = 0; r < 8; ++r) {
            float ov = __shfl_xor(minv[r], off);
            int   oi = __shfl_xor(mini[r], off);
            if (ov < minv[r] || (ov == minv[r] && oi < mini[r])) {
                minv[r] = ov; mini[r] = oi;
            }
        }
    }
    // K-split merge: half-1 posts, half-0 merges (strict < keeps low
    // idx) + computes the fused loss from the winning min value.
    if (grp == 1 && col == 0) {
#pragma unroll
        for (int r = 0; r < 8; ++r) {
            int rl = (r >> 2) * 16 + quad * 4 + (r & 3);
            mrg[wv][rl] = make_float2(minv[r], __int_as_float(mini[r]));
        }
    }
    __syncthreads();
    if (grp == 0) {
        // full row-norms for this wave's rows (r 0..3: af0 rows
        // quad*4+r; r 4..7: af1 rows 16+quad*4+(r&3))
        float z2r[8];
#pragma unroll
        for (int r = 0; r < 4; ++r) {
            z2r[r]     = __shfl(z2a, quad * 4 + r);
            z2r[4 + r] = __shfl(z2b, quad * 4 + r);
        }
        float lsum = 0.f;
        if (col == 0) {
#pragma unroll
            for (int r = 0; r < 8; ++r) {
                int rl = (r >> 2) * 16 + quad * 4 + (r & 3);
                float2 m2 = mrg[wv][rl];
                float bv = minv[r]; int bi = mini[r];
                if (m2.x < bv) { bv = m2.x; bi = __float_as_int(m2.y); }
                idx_s[wv * 32 + rl] = bi;
                // ||z-e||^2 = ||z||^2 + 2*(0.5||e||^2 - <z,e>)
                lsum += z2r[r] + 2.f * bv;
            }
        }
        lsum += __shfl_xor(lsum, 16);
        lsum += __shfl_xor(lsum, 32);
        if (lane == 0) wred[wv] = lsum;
    }
    __syncthreads();

    // ---- epilogue: gather emb rows -> LDS, write out (no z re-read) --
    // group g handles rows hw0 + g*64 .. +63 in two 32-row passes
    float* zqg = (float*)smem + grp * 8224;   // 32 x 257 floats
    int tt = t & 255;
    for (int s = 0; s < 2; ++s) {
        if (s) __syncthreads();
#pragma unroll 4
        for (int i = 0; i < 32; ++i)
            zqg[i * 257 + tt] =
                emb[(size_t)idx_s[grp * 64 + s * 32 + i] * D_DIM + tt];
        __syncthreads();
        int j = tt & 31, dq = tt >> 5;
#pragma unroll 4
        for (int p = 0; p < 32; ++p) {
            int d = dq * 32 + p;
            size_t o = (size_t)(b * D_DIM + d) * HW
                       + hw0 + grp * 64 + s * 32 + j;
            out[o] = zqg[j * 257 + d];        // z_q_st == z_q numerically
        }
    }
    if (t == 0) {
        float s4 = wred[0] + wred[1] + wred[2] + wred[3];
        atomicAdd(loss_acc, s4);
        __threadfence();
        if (atomicAdd(cnt, 1u) == NBLK - 1) {
            // all blocks' loss adds are visible at the L2 atomic point
            float total = atomicAdd(loss_acc, 0.0f);
            out[TOT_ELEMS] = total * (1.25f / (float)TOT_ELEMS);
        }
    }
}

// ------------------------------------------------------------------
extern "C" void kernel_launch(void* const* d_in, const int* in_sizes, int n_in,
                              void* d_out, int out_size, void* d_ws, size_t ws_size,
                              hipStream_t stream) {
    const float* z   = (const float*)d_in[0];   // [32,256,32,32]
    const float* emb = (const float*)d_in[1];   // [1024,256]
    float* out = (float*)d_out;                 // [8388608 z_q_st][1 loss]

    char* ws = (char*)d_ws;
    float*    loss_acc = (float*)ws;            // @0
    unsigned* cnt      = (unsigned*)(ws + 4);   // last-block ticket
    float*    hnorm    = (float*)(ws + 1024);   // 4 KB
    _Float16* emb_h    = (_Float16*)(ws + 8192);// 512 KB

    prep_emb<<<dim3(K_CODES), dim3(256), 0, stream>>>(emb, emb_h, hnorm,
                                                      loss_acc, cnt);
    vq_main<<<dim3(NBLK), dim3(512), 0, stream>>>(z, emb_h, emb, hnorm,
                                                  out, loss_acc, cnt);
}